// Round 5
// baseline (24231.346 us; speedup 1.0000x reference)
//
#include <hip/hip_runtime.h>
#include <math.h>
#include <stdint.h>

// ---------------- problem constants ----------------
#define NB   64
#define TE   256
#define TD   200
#define MR   160

typedef _Float16 h2 __attribute__((ext_vector_type(2)));

__device__ __forceinline__ float dot2f(h2 a, h2 b, float c){
  return __builtin_amdgcn_fdot2(a, b, c, false);
}
__device__ __forceinline__ h2 u2h(unsigned u){ return __builtin_bit_cast(h2, u); }
__device__ __forceinline__ unsigned h2u(h2 h){ return __builtin_bit_cast(unsigned, h); }

__device__ __forceinline__ float sigmf(float x){
  return __fdividef(1.f, 1.f + __expf(-x));
}
__device__ __forceinline__ float tanhf_(float x){
  float ax = fabsf(x);
  float e  = __expf(-2.f*ax);
  float r  = __fdividef(1.f - e, 1.f + e);
  return copysignf(r, x);
}

// ---------------- workspace layout (bytes) ----------------
static constexpr size_t OFF_PM   = 0;            // f16 [B][t'][d]
static constexpr size_t OFF_ENCH = 8388608;      // f16 [B][t'][d]
static constexpr size_t OFF_GIP  = 16777216;     // f16 [TD][768 o][64 b]
static constexpr size_t OFF_PST  = 36438016;     // f16 [TD][512 o][64 b]
static constexpr size_t OFF_G    = 49545216;     // 6 gather bufs, each [2 par][128 kp][64 b] uint
static constexpr size_t OFF_FLG  = 49938432;     // 64 uflags + 64 bflags, stride 8 uints
static constexpr size_t OFF_WU   = 49942528;     // unit-block weight pool: 64 x 10240 uints
static constexpr size_t OFF_WQ   = 52563968;     // q_w [256 o][128 kp] uint
static constexpr size_t OFF_WA   = 52695040;     // aux pool (h2 slots)
static constexpr size_t WS_NEEDED= 53334016;

// gather word offsets (uints)
static constexpr int GW_HA = 0;
static constexpr int GW_CT = 16384;
static constexpr int GW_D  = 32768;
static constexpr int GW_D2 = 49152;
static constexpr int GW_H1 = 65536;
static constexpr int GW_H2 = 81920;
static constexpr size_t G_BYTES = 393216 + 4096;   // gathers + flags (contiguous)

// aux pool offsets (h2 slots)
static constexpr size_t A_PW1  = 0;        // [80 kp][256]
static constexpr size_t A_PW2  = 20480;    // [128 kp][128]
static constexpr size_t A_WIHP = 36864;    // [64 kp][768]
static constexpr size_t A_MEMW = 86016;    // [128 kp][256]
static constexpr size_t A_MELW = 118784;   // [256 kp][160]

// ---------------- conv: generic f32 (O,K) -> f16 [kp][O] (aux pool) ----------------
__global__ void k_conv(const float* __restrict__ src, char* __restrict__ ws,
                       unsigned off_h2, int O, int Kh, int k0, int ld){
  int i = blockIdx.x*256 + threadIdx.x;
  if (i >= O*Kh) return;
  int o = i % O, kp = i / O;
  _Float16* dst = (_Float16*)(ws + OFF_WA) + 2*((size_t)off_h2 + i);
  dst[0] = (_Float16)src[(size_t)o*ld + k0 + 2*kp    ];
  dst[1] = (_Float16)src[(size_t)o*ld + k0 + 2*kp + 1];
}

// ---------------- conv: GRU pair -> per-block image, kh-swizzled ----------------
// image slot = g*10240 + base + u*768 + s*128 + kh*32 + ((kp&31) + 8*kh)&31
__global__ void k_conv_u6(const float* __restrict__ wih, const float* __restrict__ whh,
                          char* __restrict__ ws, int dstbase, int k0, int ld_ih){
  int i = blockIdx.x*256 + threadIdx.x;
  if (i >= 196608) return;
  int kp = i & 127, t1 = i >> 7;
  int s = t1 % 6, jj = t1 / 6;          // jj = output unit 0..255
  int g = jj >> 2, u = jj & 3;
  const float* src; int row, col, ld;
  if (s < 3){ src = wih; row = s*256 + jj;     col = k0 + 2*kp; ld = ld_ih; }
  else      { src = whh; row = (s-3)*256 + jj; col = 2*kp;      ld = 256; }
  h2 p; p.x = (_Float16)src[(size_t)row*ld + col]; p.y = (_Float16)src[(size_t)row*ld + col + 1];
  int kh = kp >> 5;
  int rot = ((kp & 31) + 8*kh) & 31;
  ((unsigned*)(ws + OFF_WU))[(size_t)g*10240 + dstbase + u*768 + s*128 + kh*32 + rot] = h2u(p);
}

// ---------------- conv: proj -> [g][9216 + u*256 + kh*64 + rot] ----------------
__global__ void k_conv_p4(const float* __restrict__ pw, char* __restrict__ ws){
  int i = blockIdx.x*256 + threadIdx.x;
  if (i >= 65536) return;
  int kg = i & 255, jj = i >> 8;
  h2 p; p.x = (_Float16)pw[(size_t)jj*512 + 2*kg]; p.y = (_Float16)pw[(size_t)jj*512 + 2*kg + 1];
  int kh = kg >> 6, k2 = kg & 63;
  int rot = (k2 + 8*kh) & 63;
  ((unsigned*)(ws + OFF_WU))[(size_t)(jj>>2)*10240 + 9216 + (jj&3)*256 + kh*64 + rot] = h2u(p);
}

// ---------------- conv: q_w -> [o][kp] ----------------
__global__ void k_conv_qT(const float* __restrict__ qw, char* __restrict__ ws){
  int i = blockIdx.x*256 + threadIdx.x;
  if (i >= 32768) return;
  int kp = i & 127, o = i >> 7;
  h2 p; p.x = (_Float16)qw[(size_t)o*256 + 2*kp]; p.y = (_Float16)qw[(size_t)o*256 + 2*kp + 1];
  ((unsigned*)(ws + OFF_WQ))[i] = h2u(p);
}

// ---------------- k_pm: processed_memory rows [b][t'][d] + enc f16 ----------------
__global__ void k_pm(const float* __restrict__ enc, char* __restrict__ ws){
  int bt = blockIdx.x;             // b*256 + t
  int j  = threadIdx.x;
  const h2* mw = (const h2*)(ws + OFF_WA) + A_MEMW;
  _Float16* pm   = (_Float16*)(ws + OFF_PM);
  _Float16* encH = (_Float16*)(ws + OFF_ENCH);
  __shared__ _Float16 e[256];
  float ev = enc[(size_t)bt*256 + j];
  e[j] = (_Float16)ev;
  encH[(size_t)bt*256 + j] = (_Float16)ev;
  __syncthreads();
  const h2* e2 = (const h2*)e;
  float acc = 0.f;
  #pragma unroll 8
  for (int kp=0; kp<128; ++kp) acc = dot2f(mw[kp*256 + j], e2[kp], acc);
  pm[(size_t)bt*256 + j] = (_Float16)acc;
}

// ---------------- k_pre: prenet + gi_pre -> [t][o][b] ----------------
__global__ void k_pre(const float* __restrict__ xin, const float* __restrict__ b1,
                      const float* __restrict__ b2, const float* __restrict__ bih,
                      char* __restrict__ ws){
  int bt = blockIdx.x;             // b*TD + t
  int b = bt / TD, t = bt % TD;
  int j = threadIdx.x;
  const h2* w1 = (const h2*)(ws + OFF_WA) + A_PW1;
  const h2* w2 = (const h2*)(ws + OFF_WA) + A_PW2;
  const h2* wp = (const h2*)(ws + OFF_WA) + A_WIHP;
  _Float16* gipT = (_Float16*)(ws + OFF_GIP);
  __shared__ _Float16 xh[160];
  __shared__ _Float16 a1[256];
  __shared__ _Float16 pr[128];
  if (j < 160)
    xh[j] = (t==0) ? (_Float16)0.f : (_Float16)xin[((size_t)b*TD + (t-1))*MR + j];
  __syncthreads();
  {
    const h2* x2 = (const h2*)xh;
    float acc = b1[j];
    #pragma unroll 8
    for (int kp=0; kp<80; ++kp) acc = dot2f(w1[kp*256 + j], x2[kp], acc);
    a1[j] = (_Float16)fmaxf(acc, 0.f);
  }
  __syncthreads();
  if (j < 128){
    const h2* x2 = (const h2*)a1;
    float acc = b2[j];
    #pragma unroll 8
    for (int kp=0; kp<128; ++kp) acc = dot2f(w2[kp*128 + j], x2[kp], acc);
    pr[j] = (_Float16)fmaxf(acc, 0.f);
  }
  __syncthreads();
  {
    const h2* p2 = (const h2*)pr;
    for (int o=j; o<768; o+=256){
      float acc = bih[o];
      #pragma unroll 8
      for (int kp=0; kp<64; ++kp) acc = dot2f(wp[kp*768 + o], p2[kp], acc);
      gipT[((size_t)t*768 + o)*64 + b] = (_Float16)acc;
    }
  }
}

// ---------------- gemm helpers (unit role) ----------------
__device__ __forceinline__ void acc4u(float* a, h2 w0, h2 w1, uint4 xa, uint4 xb){
  a[0]=dot2f(w0,u2h(xa.x),a[0]); a[0]=dot2f(w1,u2h(xb.x),a[0]);
  a[1]=dot2f(w0,u2h(xa.y),a[1]); a[1]=dot2f(w1,u2h(xb.y),a[1]);
  a[2]=dot2f(w0,u2h(xa.z),a[2]); a[2]=dot2f(w1,u2h(xb.z),a[2]);
  a[3]=dot2f(w0,u2h(xa.w),a[3]); a[3]=dot2f(w1,u2h(xb.w),a[3]);
}

// 6-stream dual-operand GEMV partials; weight reads use the kh-swizzled layout
__device__ __forceinline__ void gemm6(const unsigned* __restrict__ Xg,
                                      const unsigned* __restrict__ Yg,
                                      const unsigned* __restrict__ wu,
                                      int bq, int kh, float* acc){
  #pragma unroll
  for (int i=0;i<24;++i) acc[i]=0.f;
  const int khb = kh*32, rb = 8*kh;
  #pragma unroll 4
  for (int kk=0; kk<16; ++kk){
    const int kp = khb + 2*kk;                 // logical k-pair index
    const int wk = khb + ((2*kk + rb) & 31);   // physical (swizzled) slot
    uint4 xa = *(const uint4*)(Xg + kp*64       + bq*4);
    uint4 xb = *(const uint4*)(Xg + (kp+1)*64   + bq*4);
    uint4 ya = *(const uint4*)(Yg + kp*64       + bq*4);
    uint4 yb = *(const uint4*)(Yg + (kp+1)*64   + bq*4);
    #pragma unroll
    for (int s=0;s<3;++s){
      uint2 w = *(const uint2*)(wu + s*128 + wk);
      acc4u(acc + s*4, u2h(w.x), u2h(w.y), xa, xb);
    }
    #pragma unroll
    for (int s=3;s<6;++s){
      uint2 w = *(const uint2*)(wu + s*128 + wk);
      acc4u(acc + s*4, u2h(w.x), u2h(w.y), ya, yb);
    }
  }
}

__device__ __forceinline__ void red24(float* acc){
  #pragma unroll
  for (int i=0;i<24;++i){
    acc[i] += __shfl_xor(acc[i], 1, 64);
    acc[i] += __shfl_xor(acc[i], 2, 64);
  }
}

// ---------------- K4: cooperative decoder, distributed-flag barriers ----------------
// blocks 0..63: unit role (4 output units, weights LDS-resident)
// blocks 64..127: batch role (1 batch; pm + q_w register-resident)
__global__ __launch_bounds__(256, 1) void k_dec(
    const int*   __restrict__ memlen,
    const float* __restrict__ att_bhh,
    const float* __restrict__ vw,
    const float* __restrict__ proj_b,
    const float* __restrict__ g1_bih, const float* __restrict__ g1_bhh,
    const float* __restrict__ g2_bih, const float* __restrict__ g2_bhh,
    float* __restrict__ out, char* __restrict__ ws)
{
  const int tid = threadIdx.x;
  const int gid = blockIdx.x;

  unsigned* G    = (unsigned*)(ws + OFF_G);
  unsigned* ufl  = (unsigned*)(ws + OFF_FLG);        // 64 cells, stride 8 uints
  unsigned* bfl  = ufl + 512;                        // 64 cells, stride 8 uints

  __shared__ __align__(16) unsigned Wl[10240];   // 40 KB unit weights
  __shared__ float vl[256], qf[256], sc[256], al[256], part[512], red2[4];
  __shared__ unsigned hcol[128];

  // arrive: all block writes done -> one release store of a sequence number
  auto arrive = [&](unsigned* cell, unsigned seq){
    __syncthreads();
    if (tid==0)
      __hip_atomic_store(cell, seq, __ATOMIC_RELEASE, __HIP_MEMORY_SCOPE_AGENT);
  };
  // wait: lanes 0..63 poll 64 distinct flag cells in parallel (no RMW contention)
  auto waitf = [&](unsigned* base, unsigned seq){
    if (tid < 64){
      while (__hip_atomic_load(base + tid*8, __ATOMIC_ACQUIRE, __HIP_MEMORY_SCOPE_AGENT) < seq)
        __builtin_amdgcn_s_sleep(1);
    }
    __syncthreads();
  };

  if (gid < 64){
    // ================== unit role ==================
    const int g  = gid;
    const int b  = tid & 63, u = tid >> 6;
    const int bq = b >> 2,  kh = b & 3;
    const int j  = g*4 + u;
    unsigned* mycell = ufl + g*8;

    { // weights -> LDS (once)
      const uint4* s4 = (const uint4*)(ws + OFF_WU) + (size_t)g*2560;
      uint4* d4 = (uint4*)Wl;
      #pragma unroll
      for (int r=0;r<10;++r) d4[r*256 + tid] = s4[r*256 + tid];
    }
    // biases -> regs
    const float aR = att_bhh[j], aZ = att_bhh[256+j], aN = att_bhh[512+j];
    const float i1R=g1_bih[j], i1Z=g1_bih[256+j], i1N=g1_bih[512+j];
    const float h1R=g1_bhh[j], h1Z=g1_bhh[256+j], h1N=g1_bhh[512+j];
    const float i2R=g2_bih[j], i2Z=g2_bih[256+j], i2N=g2_bih[512+j];
    const float h2R=g2_bhh[j], h2Z=g2_bhh[256+j], h2N=g2_bhh[512+j];
    const float pjb = proj_b[j];
    const _Float16* gipT = (const _Float16*)(ws + OFF_GIP);
    _Float16* pst = (_Float16*)(ws + OFF_PST);
    const unsigned* wu6 = Wl + u*768;
    const int hwi = (j>>1)*128 + 2*b + (j&1);     // f16 index in a gather buffer
    float hAr=0.f, h1r=0.f, h2r=0.f;
    __syncthreads();

    #pragma unroll 1
    for (int t=0; t<TD; ++t){
      const int pa = t & 1, pv = pa ^ 1;
      const unsigned s3t = 3u*t;
      float acc[24];
      //---- S1: attention GRU (X=ctx(t-1), Y=hA(t-1))
      gemm6(G + GW_CT + pv*8192, G + GW_HA + pv*8192, wu6, bq, kh, acc);
      red24(acc);
      {
        const _Float16* gp = gipT + (size_t)t*768*64;
        float gir = acc[0*4+kh] + (float)gp[(size_t)j*64 + b];
        float giz = acc[1*4+kh] + (float)gp[(size_t)(256+j)*64 + b];
        float gin = acc[2*4+kh] + (float)gp[(size_t)(512+j)*64 + b];
        float ghr = acc[3*4+kh] + aR, ghz = acc[4*4+kh] + aZ, ghn = acc[5*4+kh] + aN;
        float r = sigmf(gir+ghr), z = sigmf(giz+ghz);
        float n = tanhf_(gin + r*ghn);
        float h = (1.f-z)*n + z*hAr; hAr = h;
        ((_Float16*)(G + GW_HA + pa*8192))[hwi] = (_Float16)h;
      }
      arrive(mycell, s3t+1);          // hA(t) published
      waitf(bfl, (unsigned)t+1);      // ctx(t) ready (and transitively all hA(t))
      //---- S2: d = [hA(t), ctx(t)] @ proj.T + b
      float dv;
      {
        float a4[4] = {0.f,0.f,0.f,0.f};
        const unsigned* Ag = (kh<2) ? (G + GW_HA + pa*8192) : (G + GW_CT + pa*8192);
        const unsigned* wp = Wl + 9216 + u*256 + kh*64;
        const int rb2 = 8*kh;
        #pragma unroll 4
        for (int kk=0; kk<32; ++kk){
          const int k2 = 2*kk;
          const int kl = (kh&1)*64 + k2;
          uint4 xa = *(const uint4*)(Ag + kl*64     + bq*4);
          uint4 xb = *(const uint4*)(Ag + (kl+1)*64 + bq*4);
          uint2 w  = *(const uint2*)(wp + ((k2 + rb2) & 63));
          acc4u(a4, u2h(w.x), u2h(w.y), xa, xb);
        }
        #pragma unroll
        for (int i=0;i<4;++i){ a4[i] += __shfl_xor(a4[i],1,64); a4[i] += __shfl_xor(a4[i],2,64); }
        dv = a4[kh] + pjb;
        ((_Float16*)(G + GW_D + pa*8192))[hwi] = (_Float16)dv;
      }
      arrive(mycell, s3t+2);
      waitf(ufl, s3t+2);              // all d(t) ready
      //---- S3: GRU1 (X=d(t), Y=h1(t-1)) + residual
      gemm6(G + GW_D + pa*8192, G + GW_H1 + pv*8192, wu6 + 3072, bq, kh, acc);
      red24(acc);
      {
        float gir = acc[0*4+kh] + i1R, giz = acc[1*4+kh] + i1Z, gin = acc[2*4+kh] + i1N;
        float ghr = acc[3*4+kh] + h1R, ghz = acc[4*4+kh] + h1Z, ghn = acc[5*4+kh] + h1N;
        float r = sigmf(gir+ghr), z = sigmf(giz+ghz);
        float n = tanhf_(gin + r*ghn);
        float h = (1.f-z)*n + z*h1r; h1r = h;
        float d2 = h + dv; dv = d2;
        ((_Float16*)(G + GW_H1 + pa*8192))[hwi] = (_Float16)h;
        ((_Float16*)(G + GW_D2 + pa*8192))[hwi] = (_Float16)d2;
      }
      arrive(mycell, s3t+3);
      waitf(ufl, s3t+3);              // all d2(t) ready
      //---- S4: GRU2 (X=d2(t), Y=h2(t-1)) + residual -> pst
      gemm6(G + GW_D2 + pa*8192, G + GW_H2 + pv*8192, wu6 + 6144, bq, kh, acc);
      red24(acc);
      {
        float gir = acc[0*4+kh] + i2R, giz = acc[1*4+kh] + i2Z, gin = acc[2*4+kh] + i2N;
        float ghr = acc[3*4+kh] + h2R, ghz = acc[4*4+kh] + h2Z, ghn = acc[5*4+kh] + h2N;
        float r = sigmf(gir+ghr), z = sigmf(giz+ghz);
        float n = tanhf_(gin + r*ghn);
        float h = (1.f-z)*n + z*h2r; h2r = h;
        float d3 = h + dv;
        ((_Float16*)(G + GW_H2 + pa*8192))[hwi] = (_Float16)h;
        pst[((size_t)t*512 + j)*64 + b] = (_Float16)d3;
      }
      // h2(t)/pst published by next iteration's arrive(3(t+1)+1)
    }
  } else {
    // ================== batch role ==================
    const int b = gid - 64;
    unsigned* mycell = bfl + b*8;
    unsigned pmreg[128], qwreg[128];
    { // pm column (this thread's t'=tid) and q_w row (o=tid) -> registers
      const uint4* ps = (const uint4*)(ws + OFF_PM) + ((size_t)b*TE + tid)*32;
      #pragma unroll
      for (int r=0;r<32;++r){
        uint4 v = ps[r];
        pmreg[4*r]=v.x; pmreg[4*r+1]=v.y; pmreg[4*r+2]=v.z; pmreg[4*r+3]=v.w;
      }
      const uint4* qs = (const uint4*)(ws + OFF_WQ) + (size_t)tid*32;
      #pragma unroll
      for (int r=0;r<32;++r){
        uint4 v = qs[r];
        qwreg[4*r]=v.x; qwreg[4*r+1]=v.y; qwreg[4*r+2]=v.z; qwreg[4*r+3]=v.w;
      }
    }
    vl[tid] = vw[tid];
    const int ml = memlen[b];
    const unsigned* encW = (const unsigned*)(ws + OFF_ENCH) + (size_t)b*TE*128;
    float* outA = out + (size_t)NB*TD*MR + (size_t)b*TD*TE;
    _Float16* pst = (_Float16*)(ws + OFF_PST);
    const int dp = tid & 127, th = tid >> 7;
    __syncthreads();

    #pragma unroll 1
    for (int t=0; t<TD; ++t){
      const int pa = t & 1;
      waitf(ufl, 3u*t+1);             // hA(t) ready from all unit blocks
      if (tid < 128) hcol[tid] = (G + GW_HA + pa*8192)[tid*64 + b];
      __syncthreads();
      //---- q = hA @ q_w.T
      {
        float qa = 0.f;
        #pragma unroll
        for (int kp=0; kp<128; ++kp) qa = dot2f(u2h(qwreg[kp]), u2h(hcol[kp]), qa);
        qf[tid] = qa;
      }
      __syncthreads();
      //---- score[t'=tid] = sum_d v[d]*tanh(pm[t'][d] + q[d])
      {
        float s = 0.f;
        #pragma unroll
        for (int dpp=0; dpp<128; ++dpp){
          h2 pvv = u2h(pmreg[dpp]);
          s += vl[2*dpp]   * tanhf_((float)pvv.x + qf[2*dpp]);
          s += vl[2*dpp+1] * tanhf_((float)pvv.y + qf[2*dpp+1]);
        }
        sc[tid] = (tid < ml) ? s : -INFINITY;
      }
      __syncthreads();
      //---- softmax over 256 (4 waves)
      {
        float v = sc[tid];
        #pragma unroll
        for (int o=32;o>0;o>>=1) v = fmaxf(v, __shfl_down(v,o,64));
        if ((tid&63)==0) red2[tid>>6] = v;
        __syncthreads();
        float m = fmaxf(fmaxf(red2[0],red2[1]), fmaxf(red2[2],red2[3]));
        __syncthreads();
        float e = __expf(sc[tid]-m);
        float sv = e;
        #pragma unroll
        for (int o=32;o>0;o>>=1) sv += __shfl_down(sv,o,64);
        if ((tid&63)==0) red2[tid>>6] = sv;
        __syncthreads();
        float sum = red2[0]+red2[1]+red2[2]+red2[3];
        float a = e*__fdividef(1.f, sum);
        al[tid] = a;
        outA[(size_t)t*TE + tid] = a;
      }
      __syncthreads();
      //---- ctx[d] = sum_t' al[t']*enc[t'][d]  (2-way t' split)
      {
        float c0=0.f, c1=0.f;
        #pragma unroll 8
        for (int tp=th*128; tp<th*128+128; ++tp){
          float a = al[tp];
          h2 e = u2h(encW[(size_t)tp*128 + dp]);
          c0 += a*(float)e.x; c1 += a*(float)e.y;
        }
        part[tid]       = c0;
        part[256 + tid] = c1;
      }
      __syncthreads();
      if (tid < 128){
        float c0 = part[tid] + part[128+tid];
        float c1 = part[256+tid] + part[384+tid];
        h2 c; c.x = (_Float16)c0; c.y = (_Float16)c1;
        (G + GW_CT + pa*8192)[tid*64 + b] = h2u(c);
        pst[((size_t)t*512 + 256 + 2*tid)*64 + b] = c.x;
        pst[((size_t)t*512 + 257 + 2*tid)*64 + b] = c.y;
      }
      arrive(mycell, (unsigned)t+1);  // ctx(t) published
    }
  }
}

// ---------------- K5: mel + stop projections ----------------
__global__ void k_post(const float* __restrict__ mel_b, const float* __restrict__ stop_w,
                       const float* __restrict__ stop_b, float* __restrict__ out,
                       char* __restrict__ ws){
  int bt = blockIdx.x;             // b*TD + t
  int b = bt / TD, t = bt % TD;
  int j = threadIdx.x;
  const h2* wm = (const h2*)(ws + OFF_WA) + A_MELW;
  const _Float16* pst = (const _Float16*)(ws + OFF_PST);
  __shared__ _Float16 pl[512];
  pl[2*j]   = pst[((size_t)t*512 + 2*j  )*64 + b];
  pl[2*j+1] = pst[((size_t)t*512 + 2*j+1)*64 + b];
  __syncthreads();
  const h2* p2 = (const h2*)pl;
  if (j < 160){
    float acc = mel_b[j];
    #pragma unroll 8
    for (int kp=0; kp<256; ++kp) acc = dot2f(wm[kp*160 + j], p2[kp], acc);
    out[(size_t)bt*MR + j] = acc;
  } else if (j == 160){
    float acc = stop_b[0];
    for (int k=0; k<512; ++k) acc += stop_w[k]*(float)pl[k];
    float s = __fdividef(1.f, 1.f + __expf(-acc));
    float* os = out + (size_t)NB*TD*MR + (size_t)NB*TD*TE + (size_t)b*2*TD;
    os[2*t]   = s;
    os[2*t+1] = s;
  }
}

// ---------------- host ----------------
extern "C" void kernel_launch(void* const* d_in, const int* in_sizes, int n_in,
                              void* d_out, int out_size, void* d_ws, size_t ws_size,
                              hipStream_t stream)
{
  const float* enc     = (const float*)d_in[0];
  const float* xin     = (const float*)d_in[1];
  const int*   mlen    = (const int*)  d_in[2];
  const float* pre_w1  = (const float*)d_in[3];
  const float* pre_b1  = (const float*)d_in[4];
  const float* pre_w2  = (const float*)d_in[5];
  const float* pre_b2  = (const float*)d_in[6];
  const float* mem_w   = (const float*)d_in[7];
  const float* att_wih = (const float*)d_in[8];
  const float* att_whh = (const float*)d_in[9];
  const float* att_bih = (const float*)d_in[10];
  const float* att_bhh = (const float*)d_in[11];
  const float* q_w     = (const float*)d_in[12];
  const float* v_w     = (const float*)d_in[13];
  const float* proj_w  = (const float*)d_in[14];
  const float* proj_b  = (const float*)d_in[15];
  const float* g1_wih  = (const float*)d_in[16];
  const float* g1_whh  = (const float*)d_in[17];
  const float* g1_bih  = (const float*)d_in[18];
  const float* g1_bhh  = (const float*)d_in[19];
  const float* g2_wih  = (const float*)d_in[20];
  const float* g2_whh  = (const float*)d_in[21];
  const float* g2_bih  = (const float*)d_in[22];
  const float* g2_bhh  = (const float*)d_in[23];
  const float* mel_w   = (const float*)d_in[24];
  const float* mel_b   = (const float*)d_in[25];
  const float* stop_w  = (const float*)d_in[26];
  const float* stop_b  = (const float*)d_in[27];
  (void)in_sizes; (void)n_in; (void)out_size;

  if (ws_size < WS_NEEDED) return;

  float* out = (float*)d_out;
  char*  ws  = (char*)d_ws;

  // zero gather buffers + flags (initial state; ws is re-poisoned before each launch)
  hipMemsetAsync(ws + OFF_G, 0, G_BYTES, stream);

  auto conv = [&](const float* src, size_t off_h2, int O, int Kh, int k0, int ld){
    int n = O*Kh;
    k_conv<<<(n+255)/256, 256, 0, stream>>>(src, ws, (unsigned)off_h2, O, Kh, k0, ld);
  };
  // aux pool
  conv(pre_w1,  A_PW1,  256, 80,  0, 160);
  conv(pre_w2,  A_PW2,  128, 128, 0, 256);
  conv(att_wih, A_WIHP, 768, 64,  0, 384);
  conv(mem_w,   A_MEMW, 256, 128, 0, 256);
  conv(mel_w,   A_MELW, 160, 256, 0, 512);
  // unit-block weight images (kh-swizzled)
  k_conv_u6<<<768, 256, 0, stream>>>(att_wih, att_whh, ws, 0,    128, 384);
  k_conv_u6<<<768, 256, 0, stream>>>(g1_wih,  g1_whh,  ws, 3072, 0,   256);
  k_conv_u6<<<768, 256, 0, stream>>>(g2_wih,  g2_whh,  ws, 6144, 0,   256);
  k_conv_p4<<<256, 256, 0, stream>>>(proj_w, ws);
  k_conv_qT<<<128, 256, 0, stream>>>(q_w, ws);

  k_pm <<<NB*TE, 256, 0, stream>>>(enc, ws);
  k_pre<<<NB*TD, 256, 0, stream>>>(xin, pre_b1, pre_b2, att_bih, ws);
  k_dec<<<128, 256, 0, stream>>>(mlen, att_bhh, v_w, proj_b,
                                 g1_bih, g1_bhh, g2_bih, g2_bhh, out, ws);
  k_post<<<NB*TD, 256, 0, stream>>>(mel_b, stop_w, stop_b, out, ws);
}

// Round 6
// 20992.628 us; speedup vs baseline: 1.1543x; 1.1543x over previous
//
#include <hip/hip_runtime.h>
#include <math.h>
#include <stdint.h>

// ---------------- problem constants ----------------
#define NB   64
#define TE   256
#define TD   200
#define MR   160

typedef _Float16 h2 __attribute__((ext_vector_type(2)));

__device__ __forceinline__ float dot2f(h2 a, h2 b, float c){
  return __builtin_amdgcn_fdot2(a, b, c, false);
}
__device__ __forceinline__ h2 u2h(unsigned u){ return __builtin_bit_cast(h2, u); }
__device__ __forceinline__ unsigned h2u(h2 h){ return __builtin_bit_cast(unsigned, h); }

__device__ __forceinline__ float sigmf(float x){
  return __fdividef(1.f, 1.f + __expf(-x));
}
__device__ __forceinline__ float tanhf_(float x){
  float ax = fabsf(x);
  float e  = __expf(-2.f*ax);
  float r  = __fdividef(1.f - e, 1.f + e);
  return copysignf(r, x);
}

// ---------------- workspace layout (bytes) ----------------
static constexpr size_t OFF_PM   = 0;                       // uint [B][128 dp][256 t'] packed pm pairs
static constexpr size_t OFF_ENCH = 8388608;                 // f16 [B][t'][256 d]
static constexpr size_t OFF_GIP  = 16777216;                // f16 [B][TD][768]
static constexpr size_t OFF_P    = 36438016;                // f16 [B][TD][512]
static constexpr size_t OFF_W2   = 49545216;                // h2 pool (small mats)
static constexpr size_t OFF_W8   = 50184192;                // uint4 pool (k_dec mats)
static constexpr size_t WS_NEEDED = 52936704;

// pool A (h2 slots): [kp][O] layouts for aux kernels
static constexpr size_t A_PW1  = 0;        // [80 kp][256]
static constexpr size_t A_PW2  = 20480;    // [128 kp][128]
static constexpr size_t A_WIHP = 36864;    // [64 kp][768]
static constexpr size_t A_MEMW = 86016;    // [128 kp][256]
static constexpr size_t A_MELW = 118784;   // [256 kp][160]

// pool B (uint4 slots): [kq][O] with 8 f16 per slot
static constexpr size_t B_ATTC = 0;        // [32 kq][768]
static constexpr size_t B_ATTH = 24576;
static constexpr size_t B_G1I  = 49152;
static constexpr size_t B_G1H  = 73728;
static constexpr size_t B_G2I  = 98304;
static constexpr size_t B_G2H  = 122880;
static constexpr size_t B_PROJ = 147456;   // [64 kq][256]
static constexpr size_t B_QW   = 163840;   // [32 kq][256]

// ---------------- K1a: f32 (O,K) row-major -> f16 [kp][O] (pool A) ----------------
__global__ void k_conv(const float* __restrict__ src, char* __restrict__ ws,
                       unsigned off_h2, int O, int Kh, int k0, int ld){
  int i = blockIdx.x*256 + threadIdx.x;
  if (i >= O*Kh) return;
  int o = i % O, kp = i / O;
  _Float16* dst = (_Float16*)(ws + OFF_W2) + 2*((size_t)off_h2 + i);
  dst[0] = (_Float16)src[(size_t)o*ld + k0 + 2*kp    ];
  dst[1] = (_Float16)src[(size_t)o*ld + k0 + 2*kp + 1];
}

// ---------------- K1b: f32 (O,K) row-major -> f16 [kq][O] packed x8 (pool B) ----------------
__global__ void k_conv8(const float* __restrict__ src, char* __restrict__ ws,
                        unsigned off16, int O, int Kq, int k0, int ld){
  int i = blockIdx.x*256 + threadIdx.x;
  if (i >= O*Kq) return;
  int o = i % O, kq = i / O;
  const float* s = src + (size_t)o*ld + k0 + kq*8;
  h2 p0, p1, p2, p3;
  p0.x=(_Float16)s[0]; p0.y=(_Float16)s[1];
  p1.x=(_Float16)s[2]; p1.y=(_Float16)s[3];
  p2.x=(_Float16)s[4]; p2.y=(_Float16)s[5];
  p3.x=(_Float16)s[6]; p3.y=(_Float16)s[7];
  uint4 r; r.x=h2u(p0); r.y=h2u(p1); r.z=h2u(p2); r.w=h2u(p3);
  ((uint4*)(ws + OFF_W8))[(size_t)off16 + i] = r;
}

// ---------------- K2: packed processed_memory pmP[b][dp][t'] + enc f16 copy ----------------
__global__ void k_pm(const float* __restrict__ enc, char* __restrict__ ws){
  int bt = blockIdx.x;             // b*256 + t
  int b  = bt >> 8, t = bt & 255;
  int j  = threadIdx.x;
  const h2* mw = (const h2*)(ws + OFF_W2) + A_MEMW;
  _Float16* encH = (_Float16*)(ws + OFF_ENCH);
  __shared__ _Float16 e[256];
  __shared__ _Float16 pmsh[256];
  float ev = enc[(size_t)bt*256 + j];
  e[j] = (_Float16)ev;
  encH[(size_t)bt*256 + j] = (_Float16)ev;
  __syncthreads();
  const h2* e2 = (const h2*)e;
  float acc = 0.f;
  #pragma unroll 8
  for (int kp=0; kp<128; ++kp) acc = dot2f(mw[kp*256 + j], e2[kp], acc);
  pmsh[j] = (_Float16)acc;
  __syncthreads();
  if (j < 128){
    h2 p; p.x = pmsh[2*j]; p.y = pmsh[2*j+1];
    ((unsigned*)(ws + OFF_PM))[(size_t)b*32768 + (size_t)j*256 + t] = h2u(p);
  }
}

// ---------------- K3: prenet + gi_pre (all timesteps, parallel) ----------------
__global__ void k_pre(const float* __restrict__ xin, const float* __restrict__ b1,
                      const float* __restrict__ b2, const float* __restrict__ bih,
                      char* __restrict__ ws){
  int bt = blockIdx.x;             // b*TD + t
  int b = bt / TD, t = bt % TD;
  int j = threadIdx.x;
  const h2* w1 = (const h2*)(ws + OFF_W2) + A_PW1;
  const h2* w2 = (const h2*)(ws + OFF_W2) + A_PW2;
  const h2* wp = (const h2*)(ws + OFF_W2) + A_WIHP;
  _Float16* gip = (_Float16*)(ws + OFF_GIP) + (size_t)bt*768;
  __shared__ _Float16 xh[160];
  __shared__ _Float16 a1[256];
  __shared__ _Float16 pr[128];
  if (j < 160)
    xh[j] = (t==0) ? (_Float16)0.f : (_Float16)xin[((size_t)b*TD + (t-1))*MR + j];
  __syncthreads();
  {
    const h2* x2 = (const h2*)xh;
    float acc = b1[j];
    #pragma unroll 8
    for (int kp=0; kp<80; ++kp) acc = dot2f(w1[kp*256 + j], x2[kp], acc);
    a1[j] = (_Float16)fmaxf(acc, 0.f);
  }
  __syncthreads();
  if (j < 128){
    const h2* x2 = (const h2*)a1;
    float acc = b2[j];
    #pragma unroll 8
    for (int kp=0; kp<128; ++kp) acc = dot2f(w2[kp*128 + j], x2[kp], acc);
    pr[j] = (_Float16)fmaxf(acc, 0.f);
  }
  __syncthreads();
  {
    const h2* p2 = (const h2*)pr;
    for (int o=j; o<768; o+=256){
      float acc = bih[o];
      #pragma unroll 8
      for (int kp=0; kp<64; ++kp) acc = dot2f(wp[kp*768 + o], p2[kp], acc);
      gip[o] = (_Float16)acc;
    }
  }
}

// ---------------- k_dec helpers ----------------
__device__ __forceinline__ float d4dot(uint4 w, uint4 x, float a){
  a = dot2f(u2h(w.x), u2h(x.x), a);
  a = dot2f(u2h(w.y), u2h(x.y), a);
  a = dot2f(u2h(w.z), u2h(x.z), a);
  a = dot2f(u2h(w.w), u2h(x.w), a);
  return a;
}

// dual-operand 6-stream GEMV partials, software-pipelined (depth 1).
// thread (ks,j): ks half of K (16 kq = 128 features), output j of 256.
__device__ __forceinline__ void gemv6p(const uint4* __restrict__ wI, const uint4* __restrict__ wH,
                                       const uint4* __restrict__ xI, const uint4* __restrict__ xH,
                                       int j, int ks, float* __restrict__ scr, int tid){
  float a0=0.f,a1=0.f,a2=0.f,a3=0.f,a4=0.f,a5=0.f;
  const int k0 = ks*16;
  const uint4* pI = wI + (size_t)k0*768 + j;
  const uint4* pH = wH + (size_t)k0*768 + j;
  uint4 w0=pI[0], w1=pI[256], w2=pI[512];
  uint4 w3=pH[0], w4=pH[256], w5=pH[512];
  uint4 xi=xI[k0], xh=xH[k0];
  #pragma unroll
  for (int k=0; k<16; ++k){
    uint4 c0=w0,c1=w1,c2=w2,c3=w3,c4=w4,c5=w5, ci=xi, ch=xh;
    if (k < 15){
      pI += 768; pH += 768;
      w0=pI[0]; w1=pI[256]; w2=pI[512];
      w3=pH[0]; w4=pH[256]; w5=pH[512];
      xi=xI[k0+k+1]; xh=xH[k0+k+1];
    }
    a0=d4dot(c0,ci,a0); a1=d4dot(c1,ci,a1); a2=d4dot(c2,ci,a2);
    a3=d4dot(c3,ch,a3); a4=d4dot(c4,ch,a4); a5=d4dot(c5,ch,a5);
  }
  float* r = scr + tid*6;
  r[0]=a0; r[1]=a1; r[2]=a2; r[3]=a3; r[4]=a4; r[5]=a5;
}

// ---------------- K4: serial decoder, one block per batch, 512 threads ----------------
__global__ __launch_bounds__(512, 2) void k_dec(
    const int*   __restrict__ memlen,
    const float* __restrict__ att_bhh,
    const float* __restrict__ vw,
    const float* __restrict__ proj_b,
    const float* __restrict__ g1_bih, const float* __restrict__ g1_bhh,
    const float* __restrict__ g2_bih, const float* __restrict__ g2_bhh,
    float* __restrict__ out, char* __restrict__ ws)
{
  const int tid = threadIdx.x;
  const int b   = blockIdx.x;
  const int ks  = tid >> 8;       // split-K half
  const int j   = tid & 255;      // output / t' index

  const uint4* W8   = (const uint4*)(ws + OFF_W8);
  const uint4* wAC  = W8 + B_ATTC;
  const uint4* wAH  = W8 + B_ATTH;
  const uint4* wG1I = W8 + B_G1I;
  const uint4* wG1H = W8 + B_G1H;
  const uint4* wG2I = W8 + B_G2I;
  const uint4* wG2H = W8 + B_G2H;
  const uint4* wPRJ = W8 + B_PROJ;
  const uint4* wQ   = W8 + B_QW;

  const unsigned* pmP  = (const unsigned*)(ws + OFF_PM)   + (size_t)b*32768;
  const unsigned* encW = (const unsigned*)(ws + OFF_ENCH) + (size_t)b*TE*128;
  const _Float16* gipB = (const _Float16*)(ws + OFF_GIP)  + (size_t)b*TD*768;
  _Float16*       pstB = (_Float16*)(ws + OFF_P)          + (size_t)b*TD*512;
  float* outA = out + (size_t)NB*TD*MR + (size_t)b*TD*TE;

  __shared__ __align__(16) _Float16 hAh[256], ctxh[256], h1h[256], h2h[256], dh[256];
  __shared__ float hAf[256], h1f[256], h2f[256], df[256];
  __shared__ float qf[256], sc[256], al[256], vl[256];
  __shared__ float scr[3072];
  __shared__ float part[1024];
  __shared__ float red2[4];

  if (tid < 256){
    hAh[tid]=(_Float16)0.f; ctxh[tid]=(_Float16)0.f; h1h[tid]=(_Float16)0.f;
    h2h[tid]=(_Float16)0.f; dh[tid]=(_Float16)0.f;
    hAf[tid]=0.f; h1f[tid]=0.f; h2f[tid]=0.f; df[tid]=0.f;
    vl[tid]=vw[tid];
  }
  const int ml = memlen[b];
  __syncthreads();

  const uint4* hA4  = (const uint4*)hAh;
  const uint4* ctx4 = (const uint4*)ctxh;
  const uint4* h14  = (const uint4*)h1h;
  const uint4* h24  = (const uint4*)h2h;
  const uint4* dd4  = (const uint4*)dh;

  #pragma unroll 1
  for (int t=0; t<TD; ++t){
    //==== S1: attention GRU (xI = ctx(t-1), xH = hA(t-1)) ====
    gemv6p(wAC, wAH, ctx4, hA4, j, ks, scr, tid);
    __syncthreads();
    if (tid < 256){
      const _Float16* gp = gipB + (size_t)t*768;
      float s0 = scr[tid*6+0]+scr[(256+tid)*6+0];
      float s1 = scr[tid*6+1]+scr[(256+tid)*6+1];
      float s2 = scr[tid*6+2]+scr[(256+tid)*6+2];
      float s3 = scr[tid*6+3]+scr[(256+tid)*6+3];
      float s4 = scr[tid*6+4]+scr[(256+tid)*6+4];
      float s5 = scr[tid*6+5]+scr[(256+tid)*6+5];
      float gir = s0 + (float)gp[tid];
      float giz = s1 + (float)gp[256+tid];
      float gin = s2 + (float)gp[512+tid];
      float ghr = s3 + att_bhh[tid];
      float ghz = s4 + att_bhh[256+tid];
      float ghn = s5 + att_bhh[512+tid];
      float r = sigmf(gir+ghr), z = sigmf(giz+ghz);
      float n = tanhf_(gin + r*ghn);
      float h = (1.f-z)*n + z*hAf[tid];
      hAf[tid]=h; hAh[tid]=(_Float16)h;
    }
    __syncthreads();
    //==== S2: q = hA @ q_w.T (pipelined) ====
    {
      float a=0.f;
      const int k0 = ks*16;
      const uint4* wp = wQ + (size_t)k0*256 + j;
      uint4 w = wp[0]; uint4 xi = hA4[k0];
      #pragma unroll
      for (int k=0; k<16; ++k){
        uint4 cw=w, ci=xi;
        if (k<15){ wp += 256; w = wp[0]; xi = hA4[k0+k+1]; }
        a = d4dot(cw, ci, a);
      }
      scr[tid]=a;
    }
    __syncthreads();
    if (tid<256) qf[tid] = scr[tid]+scr[256+tid];
    __syncthreads();
    //==== S3: score[t'=j] partials over packed d-pairs ====
    {
      float s=0.f;
      const int dp0 = ks*64;
      #pragma unroll 8
      for (int dp=dp0; dp<dp0+64; ++dp){
        h2 pv = u2h(pmP[(size_t)dp*256 + j]);
        float2 qq = *(const float2*)(qf + 2*dp);
        float2 vv = *(const float2*)(vl + 2*dp);
        s += vv.x*tanhf_((float)pv.x + qq.x);
        s += vv.y*tanhf_((float)pv.y + qq.y);
      }
      scr[tid]=s;
    }
    __syncthreads();
    if (tid<256){
      float s = scr[tid]+scr[256+tid];
      sc[tid] = (tid < ml) ? s : -INFINITY;
    }
    __syncthreads();
    //==== S4: softmax (first 4 waves) ====
    {
      float v = (tid<256) ? sc[tid] : -INFINITY;
      if (tid<256){
        #pragma unroll
        for (int o=32;o>0;o>>=1) v = fmaxf(v, __shfl_down(v,o,64));
        if ((tid&63)==0) red2[tid>>6]=v;
      }
      __syncthreads();
      float m = fmaxf(fmaxf(red2[0],red2[1]), fmaxf(red2[2],red2[3]));
      __syncthreads();
      float e = 0.f;
      if (tid<256){
        e = __expf(sc[tid]-m);
        float sv = e;
        #pragma unroll
        for (int o=32;o>0;o>>=1) sv += __shfl_down(sv,o,64);
        if ((tid&63)==0) red2[tid>>6]=sv;
      }
      __syncthreads();
      if (tid<256){
        float sum = red2[0]+red2[1]+red2[2]+red2[3];
        float a = e*__fdividef(1.f,sum);
        al[tid]=a;
        outA[(size_t)t*TE + tid]=a;
      }
    }
    __syncthreads();
    //==== S5: ctx[d] = sum_t' al[t']*enc[t'][d]  (4-way t' split) ====
    {
      const int th = tid>>7, dp = tid&127;
      float c0=0.f, c1=0.f;
      #pragma unroll 8
      for (int tp=th*64; tp<th*64+64; ++tp){
        float a = al[tp];
        h2 e = u2h(encW[(size_t)tp*128 + dp]);
        c0 += a*(float)e.x; c1 += a*(float)e.y;
      }
      part[tid]=c0; part[512+tid]=c1;
    }
    __syncthreads();
    if (tid<128){
      float c0 = part[tid]     + part[128+tid] + part[256+tid] + part[384+tid];
      float c1 = part[512+tid] + part[640+tid] + part[768+tid] + part[896+tid];
      h2 c; c.x=(_Float16)c0; c.y=(_Float16)c1;
      unsigned w = h2u(c);
      ((unsigned*)ctxh)[tid] = w;
      ((unsigned*)pstB)[(size_t)t*256 + 128 + tid] = w;   // p ctx half
    }
    __syncthreads();
    //==== S6: d = [hA, ctx] @ proj_w.T + proj_b (pipelined) ====
    {
      const uint4* x4 = (ks==0) ? hA4 : ctx4;
      const uint4* wp = wPRJ + (size_t)ks*32*256 + j;
      float a=0.f;
      uint4 w = wp[0]; uint4 xi = x4[0];
      #pragma unroll
      for (int k=0; k<32; ++k){
        uint4 cw=w, ci=xi;
        if (k<31){ wp += 256; w = wp[0]; xi = x4[k+1]; }
        a = d4dot(cw, ci, a);
      }
      scr[tid]=a;
    }
    __syncthreads();
    if (tid<256){
      float dv = scr[tid]+scr[256+tid] + proj_b[tid];
      df[tid]=dv; dh[tid]=(_Float16)dv;
    }
    __syncthreads();
    //==== S7: GRU1 + residual ====
    gemv6p(wG1I, wG1H, dd4, h14, j, ks, scr, tid);
    __syncthreads();
    if (tid<256){
      float s0 = scr[tid*6+0]+scr[(256+tid)*6+0];
      float s1 = scr[tid*6+1]+scr[(256+tid)*6+1];
      float s2 = scr[tid*6+2]+scr[(256+tid)*6+2];
      float s3 = scr[tid*6+3]+scr[(256+tid)*6+3];
      float s4 = scr[tid*6+4]+scr[(256+tid)*6+4];
      float s5 = scr[tid*6+5]+scr[(256+tid)*6+5];
      float gir = s0 + g1_bih[tid];
      float giz = s1 + g1_bih[256+tid];
      float gin = s2 + g1_bih[512+tid];
      float ghr = s3 + g1_bhh[tid];
      float ghz = s4 + g1_bhh[256+tid];
      float ghn = s5 + g1_bhh[512+tid];
      float r = sigmf(gir+ghr), z = sigmf(giz+ghz);
      float n = tanhf_(gin + r*ghn);
      float h = (1.f-z)*n + z*h1f[tid];
      float dn = h + df[tid];
      h1f[tid]=h; h1h[tid]=(_Float16)h;
      df[tid]=dn; dh[tid]=(_Float16)dn;
    }
    __syncthreads();
    //==== S8: GRU2 + residual -> pst ====
    gemv6p(wG2I, wG2H, dd4, h24, j, ks, scr, tid);
    __syncthreads();
    if (tid<256){
      float s0 = scr[tid*6+0]+scr[(256+tid)*6+0];
      float s1 = scr[tid*6+1]+scr[(256+tid)*6+1];
      float s2 = scr[tid*6+2]+scr[(256+tid)*6+2];
      float s3 = scr[tid*6+3]+scr[(256+tid)*6+3];
      float s4 = scr[tid*6+4]+scr[(256+tid)*6+4];
      float s5 = scr[tid*6+5]+scr[(256+tid)*6+5];
      float gir = s0 + g2_bih[tid];
      float giz = s1 + g2_bih[256+tid];
      float gin = s2 + g2_bih[512+tid];
      float ghr = s3 + g2_bhh[tid];
      float ghz = s4 + g2_bhh[256+tid];
      float ghn = s5 + g2_bhh[512+tid];
      float r = sigmf(gir+ghr), z = sigmf(giz+ghz);
      float n = tanhf_(gin + r*ghn);
      float h = (1.f-z)*n + z*h2f[tid];
      float dn = h + df[tid];
      h2f[tid]=h; h2h[tid]=(_Float16)h;
      pstB[(size_t)t*512 + tid] = (_Float16)dn;            // p d half
    }
    __syncthreads();
  }
}

// ---------------- K5: mel + stop projections ----------------
__global__ void k_post(const float* __restrict__ mel_b, const float* __restrict__ stop_w,
                       const float* __restrict__ stop_b, float* __restrict__ out,
                       char* __restrict__ ws){
  int bt = blockIdx.x;             // b*TD + t
  int b = bt / TD, t = bt % TD;
  int j = threadIdx.x;
  const h2* wm = (const h2*)(ws + OFF_W2) + A_MELW;
  const _Float16* p = (const _Float16*)(ws + OFF_P) + (size_t)bt*512;
  __shared__ _Float16 pl[512];
  ((uint32_t*)pl)[j] = ((const uint32_t*)p)[j];
  __syncthreads();
  const h2* p2 = (const h2*)pl;
  if (j < 160){
    float acc = mel_b[j];
    #pragma unroll 8
    for (int kp=0; kp<256; ++kp) acc = dot2f(wm[kp*160 + j], p2[kp], acc);
    out[(size_t)bt*MR + j] = acc;
  } else if (j == 160){
    float acc = stop_b[0];
    for (int k=0; k<512; ++k) acc += stop_w[k]*(float)pl[k];
    float s = __fdividef(1.f, 1.f + __expf(-acc));
    float* os = out + (size_t)NB*TD*MR + (size_t)NB*TD*TE + (size_t)b*2*TD;
    os[2*t]   = s;
    os[2*t+1] = s;
  }
}

// ---------------- host ----------------
extern "C" void kernel_launch(void* const* d_in, const int* in_sizes, int n_in,
                              void* d_out, int out_size, void* d_ws, size_t ws_size,
                              hipStream_t stream)
{
  const float* enc     = (const float*)d_in[0];
  const float* xin     = (const float*)d_in[1];
  const int*   mlen    = (const int*)  d_in[2];
  const float* pre_w1  = (const float*)d_in[3];
  const float* pre_b1  = (const float*)d_in[4];
  const float* pre_w2  = (const float*)d_in[5];
  const float* pre_b2  = (const float*)d_in[6];
  const float* mem_w   = (const float*)d_in[7];
  const float* att_wih = (const float*)d_in[8];
  const float* att_whh = (const float*)d_in[9];
  const float* att_bih = (const float*)d_in[10];
  const float* att_bhh = (const float*)d_in[11];
  const float* q_w     = (const float*)d_in[12];
  const float* v_w     = (const float*)d_in[13];
  const float* proj_w  = (const float*)d_in[14];
  const float* proj_b  = (const float*)d_in[15];
  const float* g1_wih  = (const float*)d_in[16];
  const float* g1_whh  = (const float*)d_in[17];
  const float* g1_bih  = (const float*)d_in[18];
  const float* g1_bhh  = (const float*)d_in[19];
  const float* g2_wih  = (const float*)d_in[20];
  const float* g2_whh  = (const float*)d_in[21];
  const float* g2_bih  = (const float*)d_in[22];
  const float* g2_bhh  = (const float*)d_in[23];
  const float* mel_w   = (const float*)d_in[24];
  const float* mel_b   = (const float*)d_in[25];
  const float* stop_w  = (const float*)d_in[26];
  const float* stop_b  = (const float*)d_in[27];
  (void)in_sizes; (void)n_in; (void)out_size;

  if (ws_size < WS_NEEDED) return;

  float* out = (float*)d_out;
  char*  ws  = (char*)d_ws;

  auto conv = [&](const float* src, size_t off_h2, int O, int Kh, int k0, int ld){
    int n = O*Kh;
    k_conv<<<(n+255)/256, 256, 0, stream>>>(src, ws, (unsigned)off_h2, O, Kh, k0, ld);
  };
  auto conv8 = [&](const float* src, size_t off16, int O, int Kq, int k0, int ld){
    int n = O*Kq;
    k_conv8<<<(n+255)/256, 256, 0, stream>>>(src, ws, (unsigned)off16, O, Kq, k0, ld);
  };

  // pool A (aux kernels)
  conv(pre_w1,  A_PW1,  256, 80,  0, 160);
  conv(pre_w2,  A_PW2,  128, 128, 0, 256);
  conv(att_wih, A_WIHP, 768, 64,  0, 384);
  conv(mem_w,   A_MEMW, 256, 128, 0, 256);
  conv(mel_w,   A_MELW, 160, 256, 0, 512);
  // pool B (decoder)
  conv8(att_wih, B_ATTC, 768, 32, 128, 384);
  conv8(att_whh, B_ATTH, 768, 32, 0,   256);
  conv8(g1_wih,  B_G1I,  768, 32, 0,   256);
  conv8(g1_whh,  B_G1H,  768, 32, 0,   256);
  conv8(g2_wih,  B_G2I,  768, 32, 0,   256);
  conv8(g2_whh,  B_G2H,  768, 32, 0,   256);
  conv8(proj_w,  B_PROJ, 256, 64, 0,   512);
  conv8(q_w,     B_QW,   256, 32, 0,   256);

  k_pm <<<NB*TE, 256, 0, stream>>>(enc, ws);
  k_pre<<<NB*TD, 256, 0, stream>>>(xin, pre_b1, pre_b2, att_bih, ws);
  k_dec<<<NB, 512, 0, stream>>>(mlen, att_bhh, v_w, proj_b,
                                g1_bih, g1_bhh, g2_bih, g2_bhh, out, ws);
  k_post<<<NB*TD, 256, 0, stream>>>(mel_b, stop_w, stop_b, out, ws);
}

// Round 7
// 16725.331 us; speedup vs baseline: 1.4488x; 1.2551x over previous
//
#include <hip/hip_runtime.h>
#include <math.h>
#include <stdint.h>

// ---------------- problem constants ----------------
#define NB   64
#define TE   256
#define TD   200
#define MR   160

typedef _Float16 h2 __attribute__((ext_vector_type(2)));

__device__ __forceinline__ float dot2f(h2 a, h2 b, float c){
  return __builtin_amdgcn_fdot2(a, b, c, false);
}
__device__ __forceinline__ h2 u2h(unsigned u){ return __builtin_bit_cast(h2, u); }
__device__ __forceinline__ unsigned h2u(h2 h){ return __builtin_bit_cast(unsigned, h); }

__device__ __forceinline__ float sigmf(float x){
  return __fdividef(1.f, 1.f + __expf(-x));
}
__device__ __forceinline__ float tanhf_(float x){
  float ax = fabsf(x);
  float e  = __expf(-2.f*ax);
  float r  = __fdividef(1.f - e, 1.f + e);
  return copysignf(r, x);
}

// ---------------- workspace layout (bytes) ----------------
static constexpr size_t OFF_PM   = 0;                       // uint [B][128 dp][256 t'] packed pm pairs
static constexpr size_t OFF_ENCH = 8388608;                 // f16 [B][t'][256 d]
static constexpr size_t OFF_GIP  = 16777216;                // f16 [B][TD][768]
static constexpr size_t OFF_P    = 36438016;                // f16 [B][TD][512]
static constexpr size_t OFF_W2   = 49545216;                // h2 pool (small mats)
static constexpr size_t OFF_W8   = 50184192;                // uint4 pool (k_dec mats)
static constexpr size_t WS_NEEDED = 52936704;

// pool A (h2 slots): [kp][O] layouts for aux kernels
static constexpr size_t A_PW1  = 0;        // [80 kp][256]
static constexpr size_t A_PW2  = 20480;    // [128 kp][128]
static constexpr size_t A_WIHP = 36864;    // [64 kp][768]
static constexpr size_t A_MEMW = 86016;    // [128 kp][256]
static constexpr size_t A_MELW = 118784;   // [256 kp][160]

// pool B (uint4 slots): [kq][O] with 8 f16 per slot
static constexpr size_t B_ATTC = 0;        // [32 kq][768]
static constexpr size_t B_ATTH = 24576;
static constexpr size_t B_G1I  = 49152;
static constexpr size_t B_G1H  = 73728;
static constexpr size_t B_G2I  = 98304;
static constexpr size_t B_G2H  = 122880;
static constexpr size_t B_PROJ = 147456;   // [64 kq][256]
static constexpr size_t B_QW   = 163840;   // [32 kq][256]

// ---------------- K1a: f32 (O,K) row-major -> f16 [kp][O] (pool A) ----------------
__global__ void k_conv(const float* __restrict__ src, char* __restrict__ ws,
                       unsigned off_h2, int O, int Kh, int k0, int ld){
  int i = blockIdx.x*256 + threadIdx.x;
  if (i >= O*Kh) return;
  int o = i % O, kp = i / O;
  _Float16* dst = (_Float16*)(ws + OFF_W2) + 2*((size_t)off_h2 + i);
  dst[0] = (_Float16)src[(size_t)o*ld + k0 + 2*kp    ];
  dst[1] = (_Float16)src[(size_t)o*ld + k0 + 2*kp + 1];
}

// ---------------- K1b: f32 (O,K) row-major -> f16 [kq][O] packed x8 (pool B) ----------------
__global__ void k_conv8(const float* __restrict__ src, char* __restrict__ ws,
                        unsigned off16, int O, int Kq, int k0, int ld){
  int i = blockIdx.x*256 + threadIdx.x;
  if (i >= O*Kq) return;
  int o = i % O, kq = i / O;
  const float* s = src + (size_t)o*ld + k0 + kq*8;
  h2 p0, p1, p2, p3;
  p0.x=(_Float16)s[0]; p0.y=(_Float16)s[1];
  p1.x=(_Float16)s[2]; p1.y=(_Float16)s[3];
  p2.x=(_Float16)s[4]; p2.y=(_Float16)s[5];
  p3.x=(_Float16)s[6]; p3.y=(_Float16)s[7];
  uint4 r; r.x=h2u(p0); r.y=h2u(p1); r.z=h2u(p2); r.w=h2u(p3);
  ((uint4*)(ws + OFF_W8))[(size_t)off16 + i] = r;
}

// ---------------- K2: packed processed_memory pmP[b][dp][t'] + enc f16 copy ----------------
__global__ void k_pm(const float* __restrict__ enc, char* __restrict__ ws){
  int bt = blockIdx.x;             // b*256 + t
  int b  = bt >> 8, t = bt & 255;
  int j  = threadIdx.x;
  const h2* mw = (const h2*)(ws + OFF_W2) + A_MEMW;
  _Float16* encH = (_Float16*)(ws + OFF_ENCH);
  __shared__ _Float16 e[256];
  __shared__ _Float16 pmsh[256];
  float ev = enc[(size_t)bt*256 + j];
  e[j] = (_Float16)ev;
  encH[(size_t)bt*256 + j] = (_Float16)ev;
  __syncthreads();
  const h2* e2 = (const h2*)e;
  float acc = 0.f;
  #pragma unroll 8
  for (int kp=0; kp<128; ++kp) acc = dot2f(mw[kp*256 + j], e2[kp], acc);
  pmsh[j] = (_Float16)acc;
  __syncthreads();
  if (j < 128){
    h2 p; p.x = pmsh[2*j]; p.y = pmsh[2*j+1];
    ((unsigned*)(ws + OFF_PM))[(size_t)b*32768 + (size_t)j*256 + t] = h2u(p);
  }
}

// ---------------- K3: prenet + gi_pre (all timesteps, parallel) ----------------
__global__ void k_pre(const float* __restrict__ xin, const float* __restrict__ b1,
                      const float* __restrict__ b2, const float* __restrict__ bih,
                      char* __restrict__ ws){
  int bt = blockIdx.x;             // b*TD + t
  int b = bt / TD, t = bt % TD;
  int j = threadIdx.x;
  const h2* w1 = (const h2*)(ws + OFF_W2) + A_PW1;
  const h2* w2 = (const h2*)(ws + OFF_W2) + A_PW2;
  const h2* wp = (const h2*)(ws + OFF_W2) + A_WIHP;
  _Float16* gip = (_Float16*)(ws + OFF_GIP) + (size_t)bt*768;
  __shared__ _Float16 xh[160];
  __shared__ _Float16 a1[256];
  __shared__ _Float16 pr[128];
  if (j < 160)
    xh[j] = (t==0) ? (_Float16)0.f : (_Float16)xin[((size_t)b*TD + (t-1))*MR + j];
  __syncthreads();
  {
    const h2* x2 = (const h2*)xh;
    float acc = b1[j];
    #pragma unroll 8
    for (int kp=0; kp<80; ++kp) acc = dot2f(w1[kp*256 + j], x2[kp], acc);
    a1[j] = (_Float16)fmaxf(acc, 0.f);
  }
  __syncthreads();
  if (j < 128){
    const h2* x2 = (const h2*)a1;
    float acc = b2[j];
    #pragma unroll 8
    for (int kp=0; kp<128; ++kp) acc = dot2f(w2[kp*128 + j], x2[kp], acc);
    pr[j] = (_Float16)fmaxf(acc, 0.f);
  }
  __syncthreads();
  {
    const h2* p2 = (const h2*)pr;
    for (int o=j; o<768; o+=256){
      float acc = bih[o];
      #pragma unroll 8
      for (int kp=0; kp<64; ++kp) acc = dot2f(wp[kp*768 + o], p2[kp], acc);
      gip[o] = (_Float16)acc;
    }
  }
}

// ---------------- k_dec helpers ----------------
__device__ __forceinline__ float d4dot(uint4 w, uint4 x, float a){
  a = dot2f(u2h(w.x), u2h(x.x), a);
  a = dot2f(u2h(w.y), u2h(x.y), a);
  a = dot2f(u2h(w.z), u2h(x.z), a);
  a = dot2f(u2h(w.w), u2h(x.w), a);
  return a;
}

// dual-operand 6-stream GEMV partials, depth-1 software pipeline.
// thread (ks,j): ks quarter of K (8 kq = 64 features), output j of 256.
__device__ __forceinline__ void gemv6p(const uint4* __restrict__ wI, const uint4* __restrict__ wH,
                                       const uint4* __restrict__ xI, const uint4* __restrict__ xH,
                                       int j, int ks, float* __restrict__ scr, int tid){
  float a0=0.f,a1=0.f,a2=0.f,a3=0.f,a4=0.f,a5=0.f;
  const int k0 = ks*8;
  const uint4* pI = wI + (size_t)k0*768 + j;
  const uint4* pH = wH + (size_t)k0*768 + j;
  uint4 w0=pI[0], w1=pI[256], w2=pI[512];
  uint4 w3=pH[0], w4=pH[256], w5=pH[512];
  uint4 xi=xI[k0], xh=xH[k0];
  #pragma unroll
  for (int k=0; k<8; ++k){
    uint4 c0=w0,c1=w1,c2=w2,c3=w3,c4=w4,c5=w5, ci=xi, ch=xh;
    if (k < 7){
      pI += 768; pH += 768;
      w0=pI[0]; w1=pI[256]; w2=pI[512];
      w3=pH[0]; w4=pH[256]; w5=pH[512];
      xi=xI[k0+k+1]; xh=xH[k0+k+1];
    }
    a0=d4dot(c0,ci,a0); a1=d4dot(c1,ci,a1); a2=d4dot(c2,ci,a2);
    a3=d4dot(c3,ch,a3); a4=d4dot(c4,ch,a4); a5=d4dot(c5,ch,a5);
  }
  float* r = scr + tid*6;
  r[0]=a0; r[1]=a1; r[2]=a2; r[3]=a3; r[4]=a4; r[5]=a5;
}

// ---------------- K4: serial decoder, one block per batch, 1024 threads ----------------
__global__ __launch_bounds__(1024) void k_dec(
    const int*   __restrict__ memlen,
    const float* __restrict__ att_bhh,
    const float* __restrict__ vw,
    const float* __restrict__ proj_b,
    const float* __restrict__ g1_bih, const float* __restrict__ g1_bhh,
    const float* __restrict__ g2_bih, const float* __restrict__ g2_bhh,
    float* __restrict__ out, char* __restrict__ ws)
{
  const int tid = threadIdx.x;
  const int b   = blockIdx.x;
  const int ks  = tid >> 8;       // split-K quarter
  const int j   = tid & 255;      // output / t' index

  const uint4* W8   = (const uint4*)(ws + OFF_W8);
  const uint4* wAC  = W8 + B_ATTC;
  const uint4* wAH  = W8 + B_ATTH;
  const uint4* wG1I = W8 + B_G1I;
  const uint4* wG1H = W8 + B_G1H;
  const uint4* wG2I = W8 + B_G2I;
  const uint4* wG2H = W8 + B_G2H;
  const uint4* wPRJ = W8 + B_PROJ;
  const uint4* wQ   = W8 + B_QW;

  const unsigned* pmP  = (const unsigned*)(ws + OFF_PM)   + (size_t)b*32768;
  const unsigned* encW = (const unsigned*)(ws + OFF_ENCH) + (size_t)b*TE*128;
  const _Float16* gipB = (const _Float16*)(ws + OFF_GIP)  + (size_t)b*TD*768;
  _Float16*       pstB = (_Float16*)(ws + OFF_P)          + (size_t)b*TD*512;
  float* outA = out + (size_t)NB*TD*MR + (size_t)b*TD*TE;

  __shared__ __align__(16) _Float16 hAh[256], ctxh[256], h1h[256], h2h[256], dh[256];
  __shared__ float hAf[256], h1f[256], h2f[256], df[256];
  __shared__ float qf[256], sc[256], al[256], vl[256];
  __shared__ float scr[6144];
  __shared__ float part[1024];
  __shared__ float red2[4];

  if (tid < 256){
    hAh[tid]=(_Float16)0.f; ctxh[tid]=(_Float16)0.f; h1h[tid]=(_Float16)0.f;
    h2h[tid]=(_Float16)0.f; dh[tid]=(_Float16)0.f;
    hAf[tid]=0.f; h1f[tid]=0.f; h2f[tid]=0.f; df[tid]=0.f;
    vl[tid]=vw[tid];
  }
  const int ml = memlen[b];
  __syncthreads();

  const uint4* hA4  = (const uint4*)hAh;
  const uint4* ctx4 = (const uint4*)ctxh;
  const uint4* h14  = (const uint4*)h1h;
  const uint4* h24  = (const uint4*)h2h;
  const uint4* dd4  = (const uint4*)dh;

  #pragma unroll 1
  for (int t=0; t<TD; ++t){
    //==== S1: attention GRU (xI = ctx(t-1), xH = hA(t-1)) ====
    gemv6p(wAC, wAH, ctx4, hA4, j, ks, scr, tid);
    __syncthreads();
    if (tid < 256){
      const _Float16* gp = gipB + (size_t)t*768;
      float s0 = scr[tid*6+0]+scr[(256+tid)*6+0]+scr[(512+tid)*6+0]+scr[(768+tid)*6+0];
      float s1 = scr[tid*6+1]+scr[(256+tid)*6+1]+scr[(512+tid)*6+1]+scr[(768+tid)*6+1];
      float s2 = scr[tid*6+2]+scr[(256+tid)*6+2]+scr[(512+tid)*6+2]+scr[(768+tid)*6+2];
      float s3 = scr[tid*6+3]+scr[(256+tid)*6+3]+scr[(512+tid)*6+3]+scr[(768+tid)*6+3];
      float s4 = scr[tid*6+4]+scr[(256+tid)*6+4]+scr[(512+tid)*6+4]+scr[(768+tid)*6+4];
      float s5 = scr[tid*6+5]+scr[(256+tid)*6+5]+scr[(512+tid)*6+5]+scr[(768+tid)*6+5];
      float gir = s0 + (float)gp[tid];
      float giz = s1 + (float)gp[256+tid];
      float gin = s2 + (float)gp[512+tid];
      float ghr = s3 + att_bhh[tid];
      float ghz = s4 + att_bhh[256+tid];
      float ghn = s5 + att_bhh[512+tid];
      float r = sigmf(gir+ghr), z = sigmf(giz+ghz);
      float n = tanhf_(gin + r*ghn);
      float h = (1.f-z)*n + z*hAf[tid];
      hAf[tid]=h; hAh[tid]=(_Float16)h;
    }
    __syncthreads();
    //==== S2: q = hA @ q_w.T (pipelined) ====
    {
      float a=0.f;
      const int k0 = ks*8;
      const uint4* wp = wQ + (size_t)k0*256 + j;
      uint4 w = wp[0]; uint4 xi = hA4[k0];
      #pragma unroll
      for (int k=0; k<8; ++k){
        uint4 cw=w, ci=xi;
        if (k<7){ wp += 256; w = wp[0]; xi = hA4[k0+k+1]; }
        a = d4dot(cw, ci, a);
      }
      scr[tid]=a;
    }
    __syncthreads();
    if (tid<256) qf[tid] = scr[tid]+scr[256+tid]+scr[512+tid]+scr[768+tid];
    __syncthreads();
    //==== S3: score[t'=j] partials over packed d-pairs ====
    {
      float s=0.f;
      const int dp0 = ks*32;
      #pragma unroll 8
      for (int dp=dp0; dp<dp0+32; ++dp){
        h2 pv = u2h(pmP[(size_t)dp*256 + j]);
        float2 qq = *(const float2*)(qf + 2*dp);
        float2 vv = *(const float2*)(vl + 2*dp);
        s += vv.x*tanhf_((float)pv.x + qq.x);
        s += vv.y*tanhf_((float)pv.y + qq.y);
      }
      scr[tid]=s;
    }
    __syncthreads();
    if (tid<256){
      float s = scr[tid]+scr[256+tid]+scr[512+tid]+scr[768+tid];
      sc[tid] = (tid < ml) ? s : -INFINITY;
    }
    __syncthreads();
    //==== S4: softmax (first 4 waves) ====
    {
      float v = (tid<256) ? sc[tid] : -INFINITY;
      if (tid<256){
        #pragma unroll
        for (int o=32;o>0;o>>=1) v = fmaxf(v, __shfl_down(v,o,64));
        if ((tid&63)==0) red2[tid>>6]=v;
      }
      __syncthreads();
      float m = fmaxf(fmaxf(red2[0],red2[1]), fmaxf(red2[2],red2[3]));
      __syncthreads();
      float e = 0.f;
      if (tid<256){
        e = __expf(sc[tid]-m);
        float sv = e;
        #pragma unroll
        for (int o=32;o>0;o>>=1) sv += __shfl_down(sv,o,64);
        if ((tid&63)==0) red2[tid>>6]=sv;
      }
      __syncthreads();
      if (tid<256){
        float sum = red2[0]+red2[1]+red2[2]+red2[3];
        float a = e*__fdividef(1.f,sum);
        al[tid]=a;
        outA[(size_t)t*TE + tid]=a;
      }
    }
    __syncthreads();
    //==== S5: ctx[d] = sum_t' al[t']*enc[t'][d]  (8-way t' split) ====
    {
      const int tsl = tid>>7, dp = tid&127;
      float c0=0.f, c1=0.f;
      #pragma unroll 8
      for (int tp=tsl*32; tp<tsl*32+32; ++tp){
        float a = al[tp];
        h2 e = u2h(encW[(size_t)tp*128 + dp]);
        c0 += a*(float)e.x; c1 += a*(float)e.y;
      }
      part[tid]=c0;
      scr[tid]=c1;
    }
    __syncthreads();
    if (tid<128){
      float c0=0.f, c1=0.f;
      #pragma unroll
      for (int k=0;k<8;++k){ c0 += part[k*128+tid]; c1 += scr[k*128+tid]; }
      h2 c; c.x=(_Float16)c0; c.y=(_Float16)c1;
      unsigned w = h2u(c);
      ((unsigned*)ctxh)[tid] = w;
      ((unsigned*)pstB)[(size_t)t*256 + 128 + tid] = w;   // p ctx half
    }
    __syncthreads();
    //==== S6: d = [hA, ctx] @ proj_w.T + proj_b (pipelined) ====
    {
      const uint4* x4 = (ks<2) ? hA4 : ctx4;
      const int    kb = (ks<2) ? 0 : 32;
      const int    k0 = ks*16;
      const uint4* wp = wPRJ + (size_t)k0*256 + j;
      float a=0.f;
      uint4 w = wp[0]; uint4 xi = x4[k0-kb];
      #pragma unroll
      for (int k=0; k<16; ++k){
        uint4 cw=w, ci=xi;
        if (k<15){ wp += 256; w = wp[0]; xi = x4[k0-kb+k+1]; }
        a = d4dot(cw, ci, a);
      }
      scr[tid]=a;
    }
    __syncthreads();
    if (tid<256){
      float dv = scr[tid]+scr[256+tid]+scr[512+tid]+scr[768+tid] + proj_b[tid];
      df[tid]=dv; dh[tid]=(_Float16)dv;
    }
    __syncthreads();
    //==== S7: GRU1 + residual ====
    gemv6p(wG1I, wG1H, dd4, h14, j, ks, scr, tid);
    __syncthreads();
    if (tid<256){
      float s0 = scr[tid*6+0]+scr[(256+tid)*6+0]+scr[(512+tid)*6+0]+scr[(768+tid)*6+0];
      float s1 = scr[tid*6+1]+scr[(256+tid)*6+1]+scr[(512+tid)*6+1]+scr[(768+tid)*6+1];
      float s2 = scr[tid*6+2]+scr[(256+tid)*6+2]+scr[(512+tid)*6+2]+scr[(768+tid)*6+2];
      float s3 = scr[tid*6+3]+scr[(256+tid)*6+3]+scr[(512+tid)*6+3]+scr[(768+tid)*6+3];
      float s4 = scr[tid*6+4]+scr[(256+tid)*6+4]+scr[(512+tid)*6+4]+scr[(768+tid)*6+4];
      float s5 = scr[tid*6+5]+scr[(256+tid)*6+5]+scr[(512+tid)*6+5]+scr[(768+tid)*6+5];
      float gir = s0 + g1_bih[tid];
      float giz = s1 + g1_bih[256+tid];
      float gin = s2 + g1_bih[512+tid];
      float ghr = s3 + g1_bhh[tid];
      float ghz = s4 + g1_bhh[256+tid];
      float ghn = s5 + g1_bhh[512+tid];
      float r = sigmf(gir+ghr), z = sigmf(giz+ghz);
      float n = tanhf_(gin + r*ghn);
      float h = (1.f-z)*n + z*h1f[tid];
      float dn = h + df[tid];
      h1f[tid]=h; h1h[tid]=(_Float16)h;
      df[tid]=dn; dh[tid]=(_Float16)dn;
    }
    __syncthreads();
    //==== S8: GRU2 + residual -> pst ====
    gemv6p(wG2I, wG2H, dd4, h24, j, ks, scr, tid);
    __syncthreads();
    if (tid<256){
      float s0 = scr[tid*6+0]+scr[(256+tid)*6+0]+scr[(512+tid)*6+0]+scr[(768+tid)*6+0];
      float s1 = scr[tid*6+1]+scr[(256+tid)*6+1]+scr[(512+tid)*6+1]+scr[(768+tid)*6+1];
      float s2 = scr[tid*6+2]+scr[(256+tid)*6+2]+scr[(512+tid)*6+2]+scr[(768+tid)*6+2];
      float s3 = scr[tid*6+3]+scr[(256+tid)*6+3]+scr[(512+tid)*6+3]+scr[(768+tid)*6+3];
      float s4 = scr[tid*6+4]+scr[(256+tid)*6+4]+scr[(512+tid)*6+4]+scr[(768+tid)*6+4];
      float s5 = scr[tid*6+5]+scr[(256+tid)*6+5]+scr[(512+tid)*6+5]+scr[(768+tid)*6+5];
      float gir = s0 + g2_bih[tid];
      float giz = s1 + g2_bih[256+tid];
      float gin = s2 + g2_bih[512+tid];
      float ghr = s3 + g2_bhh[tid];
      float ghz = s4 + g2_bhh[256+tid];
      float ghn = s5 + g2_bhh[512+tid];
      float r = sigmf(gir+ghr), z = sigmf(giz+ghz);
      float n = tanhf_(gin + r*ghn);
      float h = (1.f-z)*n + z*h2f[tid];
      float dn = h + df[tid];
      h2f[tid]=h; h2h[tid]=(_Float16)h;
      pstB[(size_t)t*512 + tid] = (_Float16)dn;            // p d half
    }
    __syncthreads();
  }
}

// ---------------- K5: mel + stop projections ----------------
__global__ void k_post(const float* __restrict__ mel_b, const float* __restrict__ stop_w,
                       const float* __restrict__ stop_b, float* __restrict__ out,
                       char* __restrict__ ws){
  int bt = blockIdx.x;             // b*TD + t
  int b = bt / TD, t = bt % TD;
  int j = threadIdx.x;
  const h2* wm = (const h2*)(ws + OFF_W2) + A_MELW;
  const _Float16* p = (const _Float16*)(ws + OFF_P) + (size_t)bt*512;
  __shared__ _Float16 pl[512];
  ((uint32_t*)pl)[j] = ((const uint32_t*)p)[j];
  __syncthreads();
  const h2* p2 = (const h2*)pl;
  if (j < 160){
    float acc = mel_b[j];
    #pragma unroll 8
    for (int kp=0; kp<256; ++kp) acc = dot2f(wm[kp*160 + j], p2[kp], acc);
    out[(size_t)bt*MR + j] = acc;
  } else if (j == 160){
    float acc = stop_b[0];
    for (int k=0; k<512; ++k) acc += stop_w[k]*(float)pl[k];
    float s = __fdividef(1.f, 1.f + __expf(-acc));
    float* os = out + (size_t)NB*TD*MR + (size_t)NB*TD*TE + (size_t)b*2*TD;
    os[2*t]   = s;
    os[2*t+1] = s;
  }
}

// ---------------- host ----------------
extern "C" void kernel_launch(void* const* d_in, const int* in_sizes, int n_in,
                              void* d_out, int out_size, void* d_ws, size_t ws_size,
                              hipStream_t stream)
{
  const float* enc     = (const float*)d_in[0];
  const float* xin     = (const float*)d_in[1];
  const int*   mlen    = (const int*)  d_in[2];
  const float* pre_w1  = (const float*)d_in[3];
  const float* pre_b1  = (const float*)d_in[4];
  const float* pre_w2  = (const float*)d_in[5];
  const float* pre_b2  = (const float*)d_in[6];
  const float* mem_w   = (const float*)d_in[7];
  const float* att_wih = (const float*)d_in[8];
  const float* att_whh = (const float*)d_in[9];
  const float* att_bih = (const float*)d_in[10];
  const float* att_bhh = (const float*)d_in[11];
  const float* q_w     = (const float*)d_in[12];
  const float* v_w     = (const float*)d_in[13];
  const float* proj_w  = (const float*)d_in[14];
  const float* proj_b  = (const float*)d_in[15];
  const float* g1_wih  = (const float*)d_in[16];
  const float* g1_whh  = (const float*)d_in[17];
  const float* g1_bih  = (const float*)d_in[18];
  const float* g1_bhh  = (const float*)d_in[19];
  const float* g2_wih  = (const float*)d_in[20];
  const float* g2_whh  = (const float*)d_in[21];
  const float* g2_bih  = (const float*)d_in[22];
  const float* g2_bhh  = (const float*)d_in[23];
  const float* mel_w   = (const float*)d_in[24];
  const float* mel_b   = (const float*)d_in[25];
  const float* stop_w  = (const float*)d_in[26];
  const float* stop_b  = (const float*)d_in[27];
  (void)in_sizes; (void)n_in; (void)out_size;

  if (ws_size < WS_NEEDED) return;

  float* out = (float*)d_out;
  char*  ws  = (char*)d_ws;

  auto conv = [&](const float* src, size_t off_h2, int O, int Kh, int k0, int ld){
    int n = O*Kh;
    k_conv<<<(n+255)/256, 256, 0, stream>>>(src, ws, (unsigned)off_h2, O, Kh, k0, ld);
  };
  auto conv8 = [&](const float* src, size_t off16, int O, int Kq, int k0, int ld){
    int n = O*Kq;
    k_conv8<<<(n+255)/256, 256, 0, stream>>>(src, ws, (unsigned)off16, O, Kq, k0, ld);
  };

  // pool A (aux kernels)
  conv(pre_w1,  A_PW1,  256, 80,  0, 160);
  conv(pre_w2,  A_PW2,  128, 128, 0, 256);
  conv(att_wih, A_WIHP, 768, 64,  0, 384);
  conv(mem_w,   A_MEMW, 256, 128, 0, 256);
  conv(mel_w,   A_MELW, 160, 256, 0, 512);
  // pool B (decoder)
  conv8(att_wih, B_ATTC, 768, 32, 128, 384);
  conv8(att_whh, B_ATTH, 768, 32, 0,   256);
  conv8(g1_wih,  B_G1I,  768, 32, 0,   256);
  conv8(g1_whh,  B_G1H,  768, 32, 0,   256);
  conv8(g2_wih,  B_G2I,  768, 32, 0,   256);
  conv8(g2_whh,  B_G2H,  768, 32, 0,   256);
  conv8(proj_w,  B_PROJ, 256, 64, 0,   512);
  conv8(q_w,     B_QW,   256, 32, 0,   256);

  k_pm <<<NB*TE, 256, 0, stream>>>(enc, ws);
  k_pre<<<NB*TD, 256, 0, stream>>>(xin, pre_b1, pre_b2, att_bih, ws);
  k_dec<<<NB, 1024, 0, stream>>>(mlen, att_bhh, v_w, proj_b,
                                 g1_bih, g1_bhh, g2_bih, g2_bhh, out, ws);
  k_post<<<NB*TD, 256, 0, stream>>>(mel_b, stop_w, stop_b, out, ws);
}